// Round 1
// baseline (1267.060 us; speedup 1.0000x reference)
//
#include <hip/hip_runtime.h>
#include <cstdint>

// AxialAttention3D on MI355X.
// Tokens live fp32 in d_out, layout (L=13, H=48, W=96, D=512), updated in place
// by each of the three axial blocks. Workspace (all ushort):
//   wT[3] : qkv weights transposed to (N=1536, K=512) bf16   3 x 1.5 MB
//   pT    : proj weight transposed to (512,512) bf16         0.5 MB
//   lnb   : LN(tok) bf16 (59904, 512)                        61 MB
//   qkv   : (59904, 1536) bf16                               184 MB
// GEMMs: 256x256 tile, BK=64, 8 waves (2Mx4N), 128 KiB double-buffered LDS,
// 4-phase-per-K-tile interleave with COUNTED vmcnt (never drained mid-loop),
// setprio around MFMA clusters, XOR-granule swizzled global_load_lds staging
// (LDS row r slot s holds source granule s^(r&7)), bijective XCD tile swizzle.
// MFMA operands are swapped (mfma(B,A)) so each lane's acc quad is 4 consecutive
// output COLUMNS -> packed 8B bf16 stores (qkv) / float4 resid+store (proj).

#define L_DIM 13
#define H_DIM 48
#define W_DIM 96
#define D_DIM 512
#define NH    16
#define MTOK  (L_DIM * H_DIM * W_DIM)   // 59904
#define N3    (3 * D_DIM)               // 1536
#define PI_F  3.14159265358979323846f

typedef __bf16 bf16x8 __attribute__((ext_vector_type(8)));
typedef float  f32x4  __attribute__((ext_vector_type(4)));

__device__ __forceinline__ float bf2f(unsigned short u) {
    return __builtin_bit_cast(float, ((unsigned)u) << 16);
}
__device__ __forceinline__ unsigned short f2bf(float f) {
    unsigned u = __builtin_bit_cast(unsigned, f);
    u += 0x7fffu + ((u >> 16) & 1u);   // round-to-nearest-even
    return (unsigned short)(u >> 16);
}
// async global->LDS, 16B per lane; lds dest = wave-uniform base + lane*16
__device__ __forceinline__ void gload16(unsigned short* lds, const unsigned short* g) {
    __builtin_amdgcn_global_load_lds(
        (const __attribute__((address_space(1))) unsigned int*)g,
        (__attribute__((address_space(3))) unsigned int*)lds, 16, 0, 0);
}

// ---------------------------------------------------------------- W (512 x N) -> W^T (N x 512) bf16
__global__ __launch_bounds__(256) void transpose_w(const float* __restrict__ w,
                                                   unsigned short* __restrict__ wt, int N) {
    __shared__ unsigned short t[64][65];
    const int k0 = blockIdx.x * 64, n0 = blockIdx.y * 64;
    const int tid = threadIdx.x;
    #pragma unroll
    for (int j = 0; j < 16; ++j) {
        int lin = j * 256 + tid;
        int kr = lin >> 6, nc = lin & 63;
        t[kr][nc] = f2bf(w[(size_t)(k0 + kr) * N + n0 + nc]);
    }
    __syncthreads();
    #pragma unroll
    for (int j = 0; j < 16; ++j) {
        int lin = j * 256 + tid;
        int nr = lin >> 6, kc = lin & 63;
        wt[(size_t)(n0 + nr) * 512 + k0 + kc] = t[kc][nr];
    }
}

// ---------------------------------------------------------------- fused LN: src fp32 -> bf16
__global__ __launch_bounds__(256) void ln_apply(
    const float* __restrict__ src, const float* __restrict__ g,
    const float* __restrict__ bln, unsigned short* __restrict__ out)
{
    int wv = threadIdx.x >> 6, lane = threadIdx.x & 63;
    int t = blockIdx.x * 4 + wv;
    const float* p = src + (size_t)t * 512 + lane * 8;
    float4 a = *(const float4*)p, b = *(const float4*)(p + 4);
    float s  = a.x + a.y + a.z + a.w + b.x + b.y + b.z + b.w;
    float s2 = a.x*a.x + a.y*a.y + a.z*a.z + a.w*a.w + b.x*b.x + b.y*b.y + b.z*b.z + b.w*b.w;
    #pragma unroll
    for (int off = 1; off < 64; off <<= 1) {
        s  += __shfl_xor(s, off, 64);
        s2 += __shfl_xor(s2, off, 64);
    }
    float mu = s * (1.f / 512.f);
    float rs = rsqrtf(s2 * (1.f / 512.f) - mu * mu + 1e-5f);
    float4 g0 = *(const float4*)(g + lane * 8),  g1 = *(const float4*)(g + lane * 8 + 4);
    float4 b0 = *(const float4*)(bln + lane * 8), b1 = *(const float4*)(bln + lane * 8 + 4);
    unsigned short o[8];
    o[0] = f2bf((a.x - mu) * rs * g0.x + b0.x);
    o[1] = f2bf((a.y - mu) * rs * g0.y + b0.y);
    o[2] = f2bf((a.z - mu) * rs * g0.z + b0.z);
    o[3] = f2bf((a.w - mu) * rs * g0.w + b0.w);
    o[4] = f2bf((b.x - mu) * rs * g1.x + b1.x);
    o[5] = f2bf((b.y - mu) * rs * g1.y + b1.y);
    o[6] = f2bf((b.z - mu) * rs * g1.z + b1.z);
    o[7] = f2bf((b.w - mu) * rs * g1.w + b1.w);
    uint4 r;
    r.x = (unsigned)o[0] | ((unsigned)o[1] << 16);
    r.y = (unsigned)o[2] | ((unsigned)o[3] << 16);
    r.z = (unsigned)o[4] | ((unsigned)o[5] << 16);
    r.w = (unsigned)o[6] | ((unsigned)o[7] << 16);
    *(uint4*)&out[(size_t)t * 512 + lane * 8] = r;
}

// ---------------------------------------------------------------- 256x256 8-phase GEMM
// C(M x N) = A(M x K=512, row stride LDA) * B^T (B is N x 512 row-major) + bias
// !PROJ: outh bf16, row stride N3.  PROJ: outf fp32 = resid + C + bias, stride 512.
// Staging ledger per wave per K-tile: SB(4 loads)@q0, SA0(2)@q1, SA1(2)@q2.
// Waits: end-q0 vmcnt(4) [SA1(t) done], end-q3 vmcnt(2) [SB,SA0(t+1) done].
#define QUAD(mi, A) do { \
    acc[mi][0] = __builtin_amdgcn_mfma_f32_16x16x32_bf16(b0, A, acc[mi][0], 0, 0, 0); \
    acc[mi][1] = __builtin_amdgcn_mfma_f32_16x16x32_bf16(b1, A, acc[mi][1], 0, 0, 0); \
    acc[mi][2] = __builtin_amdgcn_mfma_f32_16x16x32_bf16(b2, A, acc[mi][2], 0, 0, 0); \
    acc[mi][3] = __builtin_amdgcn_mfma_f32_16x16x32_bf16(b3, A, acc[mi][3], 0, 0, 0); \
} while (0)
#define RDA(mi, ks) (*(const bf16x8*)&As[cur][wm + (mi) * 16 + lm][((((ks) * 4 + kq) ^ (lm & 7)) << 3)])
#define RDB(ni, ks) (*(const bf16x8*)&Bs[cur][wn + (ni) * 16 + lm][((((ks) * 4 + kq) ^ (lm & 7)) << 3)])

template<int LDA, int NBX, bool PROJ>
__global__ __launch_bounds__(512, 2) void gemm8p(
    const unsigned short* __restrict__ A,
    const unsigned short* __restrict__ B,
    const float* __restrict__ bias,
    const float* __restrict__ resid,
    float* __restrict__ outf,
    unsigned short* __restrict__ outh)
{
    __shared__ alignas(16) unsigned short As[2][256][64];
    __shared__ alignas(16) unsigned short Bs[2][256][64];

    // bijective XCD swizzle (m204): contiguous tile chunk per XCD
    const int nwg = NBX * 234;
    const int orig = blockIdx.y * NBX + blockIdx.x;
    const int qq = nwg >> 3, rr = nwg & 7;
    const int xcd = orig & 7, idx = orig >> 3;
    const int swz = (xcd < rr ? xcd * (qq + 1) : rr * (qq + 1) + (xcd - rr) * qq) + idx;
    const int n0 = (swz % NBX) * 256;
    const int m0 = (swz / NBX) * 256;

    const int tid = threadIdx.x, lane = tid & 63, wv = tid >> 6;
    const int wm = (wv >> 2) * 128, wn = (wv & 3) * 64;
    const int lm = lane & 15, kq = lane >> 4;
    const int rblk = lane >> 3;
    const int sc = (((lane & 7) ^ rblk) << 3);          // pre-swizzled source granule

    // staging source bases (per lane)
    const unsigned short* bsrc = B + (size_t)(n0 + wv * 32 + rblk) * 512 + sc;
    const int ar0 = (wv & 4) ? (128 + (wv & 3) * 16) : (wv * 16);  // rows needed at q0/q2
    const unsigned short* asrc = A + (size_t)(m0 + ar0 + rblk) * LDA + sc;

    f32x4 acc[8][4] = {};

    // prologue: stage K-tile 0 into buffer 0
    #pragma unroll
    for (int j = 0; j < 4; ++j)
        gload16(&Bs[0][wv * 32 + j * 8][0], bsrc + (size_t)(j * 8) * 512);
    gload16(&As[0][ar0 + 0][0], asrc);
    gload16(&As[0][ar0 + 8][0], asrc + (size_t)8 * LDA);
    gload16(&As[0][ar0 + 64][0], asrc + (size_t)64 * LDA);
    gload16(&As[0][ar0 + 72][0], asrc + (size_t)72 * LDA);
    asm volatile("s_waitcnt vmcnt(2)" ::: "memory");    // SB(0)+SA0(0) done, SA1(0) in flight
    __builtin_amdgcn_s_barrier();
    __builtin_amdgcn_sched_barrier(0);

    for (int kt = 0; kt < 8; ++kt) {
        const int cur = kt & 1, nxt = cur ^ 1;
        const int kn = (kt + 1) * 64;
        const bool st = (kt < 7);
        bf16x8 a0, a1, a2, a3, b0, b1, b2, b3;

        // ---- phase q0: mi 0-3 x ks0; stage SB(t+1)
        a0 = RDA(0, 0); a1 = RDA(1, 0); a2 = RDA(2, 0); a3 = RDA(3, 0);
        b0 = RDB(0, 0); b1 = RDB(1, 0); b2 = RDB(2, 0); b3 = RDB(3, 0);
        if (st) {
            gload16(&Bs[nxt][wv * 32 +  0][0], bsrc + (size_t) 0 * 512 + kn);
            gload16(&Bs[nxt][wv * 32 +  8][0], bsrc + (size_t) 8 * 512 + kn);
            gload16(&Bs[nxt][wv * 32 + 16][0], bsrc + (size_t)16 * 512 + kn);
            gload16(&Bs[nxt][wv * 32 + 24][0], bsrc + (size_t)24 * 512 + kn);
        }
        __builtin_amdgcn_s_barrier();
        __builtin_amdgcn_s_setprio(1);
        QUAD(0, a0); QUAD(1, a1); QUAD(2, a2); QUAD(3, a3);
        __builtin_amdgcn_s_setprio(0);
        if (st) asm volatile("s_waitcnt vmcnt(4)" ::: "memory");  // SA1(t) landed
        else    asm volatile("s_waitcnt vmcnt(0)" ::: "memory");  // tail drain
        __builtin_amdgcn_s_barrier();
        __builtin_amdgcn_sched_barrier(0);

        // ---- phase q1: mi 4-7 x ks0 (B regs reused); stage SA0(t+1)
        a0 = RDA(4, 0); a1 = RDA(5, 0); a2 = RDA(6, 0); a3 = RDA(7, 0);
        if (st) {
            gload16(&As[nxt][ar0 + 0][0], asrc + kn);
            gload16(&As[nxt][ar0 + 8][0], asrc + (size_t)8 * LDA + kn);
        }
        __builtin_amdgcn_s_barrier();
        __builtin_amdgcn_s_setprio(1);
        QUAD(4, a0); QUAD(5, a1); QUAD(6, a2); QUAD(7, a3);
        __builtin_amdgcn_s_setprio(0);
        __builtin_amdgcn_s_barrier();

        // ---- phase q2: mi 0-3 x ks1; stage SA1(t+1)
        a0 = RDA(0, 1); a1 = RDA(1, 1); a2 = RDA(2, 1); a3 = RDA(3, 1);
        b0 = RDB(0, 1); b1 = RDB(1, 1); b2 = RDB(2, 1); b3 = RDB(3, 1);
        if (st) {
            gload16(&As[nxt][ar0 + 64][0], asrc + (size_t)64 * LDA + kn);
            gload16(&As[nxt][ar0 + 72][0], asrc + (size_t)72 * LDA + kn);
        }
        __builtin_amdgcn_s_barrier();
        __builtin_amdgcn_s_setprio(1);
        QUAD(0, a0); QUAD(1, a1); QUAD(2, a2); QUAD(3, a3);
        __builtin_amdgcn_s_setprio(0);
        __builtin_amdgcn_s_barrier();

        // ---- phase q3: mi 4-7 x ks1
        a0 = RDA(4, 1); a1 = RDA(5, 1); a2 = RDA(6, 1); a3 = RDA(7, 1);
        __builtin_amdgcn_s_barrier();
        __builtin_amdgcn_s_setprio(1);
        QUAD(4, a0); QUAD(5, a1); QUAD(6, a2); QUAD(7, a3);
        __builtin_amdgcn_s_setprio(0);
        asm volatile("s_waitcnt vmcnt(2)" ::: "memory");  // SB(t+1)+SA0(t+1) landed
        __builtin_amdgcn_s_barrier();
        __builtin_amdgcn_sched_barrier(0);
    }

    // epilogue: swapped operands -> lane holds 4 consecutive COLS of row (wm+mi*16+lm)
    const int cr = kq << 2;
    if constexpr (!PROJ) {
        #pragma unroll
        for (int ni = 0; ni < 4; ++ni) {
            const int col = n0 + wn + ni * 16 + cr;
            const float4 bb = *(const float4*)&bias[col];
            #pragma unroll
            for (int mi = 0; mi < 8; ++mi) {
                const size_t off = (size_t)(m0 + wm + mi * 16 + lm) * N3 + col;
                uint2 pk;
                pk.x = (unsigned)f2bf(acc[mi][ni][0] + bb.x) | ((unsigned)f2bf(acc[mi][ni][1] + bb.y) << 16);
                pk.y = (unsigned)f2bf(acc[mi][ni][2] + bb.z) | ((unsigned)f2bf(acc[mi][ni][3] + bb.w) << 16);
                *(uint2*)&outh[off] = pk;
            }
        }
    } else {
        #pragma unroll
        for (int ni = 0; ni < 4; ++ni) {
            const int col = n0 + wn + ni * 16 + cr;
            const float4 bb = *(const float4*)&bias[col];
            #pragma unroll
            for (int mi = 0; mi < 8; ++mi) {
                const size_t off = (size_t)(m0 + wm + mi * 16 + lm) * 512 + col;
                float4 rs = *(const float4*)&resid[off];
                float4 o;
                o.x = rs.x + acc[mi][ni][0] + bb.x;
                o.y = rs.y + acc[mi][ni][1] + bb.y;
                o.z = rs.z + acc[mi][ni][2] + bb.z;
                o.w = rs.w + acc[mi][ni][3] + bb.w;
                *(float4*)&outf[off] = o;      // resid may alias outf (same element)
            }
        }
    }
}

// ---------------------------------------------------------------- MFMA attention, S in {48, 96}
template<int S, int MODE>
__global__ __launch_bounds__(256) void attn_big(
    unsigned short* __restrict__ qkv,
    const float* __restrict__ lat_grid, const float* __restrict__ lon_grid)
{
    constexpr int NQ  = S / 16;
    constexpr int SKP = (S + 31) & ~31;
    constexpr int VST = SKP + 8;
    __shared__ alignas(16) unsigned short qs[S][40];
    __shared__ alignas(16) unsigned short ks[S][40];
    __shared__ alignas(16) unsigned short vT[32][VST];
    __shared__ alignas(16) unsigned short pb[4][16][VST];

    const int n = blockIdx.x, h = blockIdx.y;
    const int tid = threadIdx.x, lane = tid & 63, wv = tid >> 6;
    int base, step;
    if (MODE == 0) { int l = n / 96, w = n - l * 96; base = l * 4608 + w; step = 96; }
    else           { base = n * 96; step = 1; }

    const float SCALE = 0.17677669529663689f;   // 1/sqrt(32)
    for (int idx = tid; idx < S * 16; idx += 256) {
        int s = idx >> 4, i = idx & 15;
        size_t ro = (size_t)(base + s * step) * N3 + h * 32;
        unsigned qp = *(const unsigned*)(qkv + ro + 2 * i);
        unsigned kp = *(const unsigned*)(qkv + ro + 512 + 2 * i);
        unsigned vp = *(const unsigned*)(qkv + ro + 1024 + 2 * i);
        float coord;
        if (MODE == 0) {
            float la = lat_grid[s];
            coord = fminf(fmaxf(la, -PI_F / 2 + 1e-6f), PI_F / 2 - 1e-6f);
        } else {
            float xp = lon_grid[s] + PI_F;
            coord = xp - floorf(xp * (0.5f / PI_F)) * (2.f * PI_F) - PI_F;
        }
        float ph = coord * exp2f(-(float)i * 0.83048202372f); // log2(1e4)/16
        float sn = sinf(ph), cs = cosf(ph);
        float q1 = bf2f((unsigned short)qp), q2 = bf2f((unsigned short)(qp >> 16));
        float k1 = bf2f((unsigned short)kp), k2 = bf2f((unsigned short)(kp >> 16));
        qs[s][i]      = f2bf((q1 * cs - q2 * sn) * SCALE);
        qs[s][16 + i] = f2bf((q1 * sn + q2 * cs) * SCALE);
        ks[s][i]      = f2bf(k1 * cs - k2 * sn);
        ks[s][16 + i] = f2bf(k1 * sn + k2 * cs);
        vT[2 * i][s]     = (unsigned short)vp;
        vT[2 * i + 1][s] = (unsigned short)(vp >> 16);
    }
    if (SKP > S) {
        for (int idx = tid; idx < 32 * (SKP - S); idx += 256)
            vT[idx / (SKP - S)][S + idx % (SKP - S)] = 0;
    }
    __syncthreads();

    const int lm = lane & 15, ko = (lane >> 4) * 8, q4 = (lane >> 4) * 4;
    f32x4 zero = {0.f, 0.f, 0.f, 0.f};
    bf16x8 vf[SKP / 32][2];
    #pragma unroll
    for (int u2 = 0; u2 < SKP / 32; ++u2)
        #pragma unroll
        for (int nh2 = 0; nh2 < 2; ++nh2)
            vf[u2][nh2] = *(const bf16x8*)&vT[nh2 * 16 + lm][u2 * 32 + ko];
    if (SKP > S) {
        for (int idx = lane; idx < 16 * (SKP - S); idx += 64)
            pb[wv][idx / (SKP - S)][S + idx % (SKP - S)] = 0;
    }

    for (int t = wv; t < NQ; t += 4) {
        bf16x8 aq = *(const bf16x8*)&qs[t * 16 + lm][ko];
        f32x4 c[NQ];
        #pragma unroll
        for (int u = 0; u < NQ; ++u) {
            bf16x8 bk = *(const bf16x8*)&ks[u * 16 + lm][ko];
            c[u] = __builtin_amdgcn_mfma_f32_16x16x32_bf16(aq, bk, zero, 0, 0, 0);
        }
        float mr[4] = {-1e30f, -1e30f, -1e30f, -1e30f}, sm[4] = {0.f, 0.f, 0.f, 0.f};
        #pragma unroll
        for (int u = 0; u < NQ; ++u)
            #pragma unroll
            for (int r = 0; r < 4; ++r) mr[r] = fmaxf(mr[r], c[u][r]);
        #pragma unroll
        for (int r = 0; r < 4; ++r)
            #pragma unroll
            for (int off = 1; off < 16; off <<= 1)
                mr[r] = fmaxf(mr[r], __shfl_xor(mr[r], off, 64));
        #pragma unroll
        for (int u = 0; u < NQ; ++u)
            #pragma unroll
            for (int r = 0; r < 4; ++r) {
                float e = __expf(c[u][r] - mr[r]);
                c[u][r] = e; sm[r] += e;
            }
        #pragma unroll
        for (int r = 0; r < 4; ++r) {
            #pragma unroll
            for (int off = 1; off < 16; off <<= 1)
                sm[r] += __shfl_xor(sm[r], off, 64);
            sm[r] = 1.f / sm[r];
        }
        #pragma unroll
        for (int u = 0; u < NQ; ++u)
            #pragma unroll
            for (int r = 0; r < 4; ++r)
                pb[wv][q4 + r][u * 16 + lm] = f2bf(c[u][r] * sm[r]);
        __builtin_amdgcn_wave_barrier();
        f32x4 o0 = zero, o1 = zero;
        #pragma unroll
        for (int u2 = 0; u2 < SKP / 32; ++u2) {
            bf16x8 ap = *(const bf16x8*)&pb[wv][lm][u2 * 32 + ko];
            o0 = __builtin_amdgcn_mfma_f32_16x16x32_bf16(ap, vf[u2][0], o0, 0, 0, 0);
            o1 = __builtin_amdgcn_mfma_f32_16x16x32_bf16(ap, vf[u2][1], o1, 0, 0, 0);
        }
        __builtin_amdgcn_wave_barrier();
        #pragma unroll
        for (int r = 0; r < 4; ++r) {
            int row = t * 16 + q4 + r;
            size_t ro = (size_t)(base + row * step) * N3 + h * 32;
            qkv[ro + lm]      = f2bf(o0[r]);
            qkv[ro + 16 + lm] = f2bf(o1[r]);
        }
    }
}

// ---------------------------------------------------------------- MFMA attention, S=13 (lev)
__global__ __launch_bounds__(256) void attn_small(unsigned short* __restrict__ qkv)
{
    __shared__ alignas(16) unsigned short qs[4][16][40];
    __shared__ alignas(16) unsigned short ks[4][16][40];
    __shared__ alignas(16) unsigned short vT[4][32][40];
    __shared__ alignas(16) unsigned short pb[4][16][40];
    const int tid = threadIdx.x, lane = tid & 63, wv = tid >> 6;
    const int pair = blockIdx.x * 4 + wv;
    const int n = pair >> 4, h = pair & 15;
    const int base = n, step = 4608;

    for (int idx = lane; idx < 13 * 16; idx += 64) {
        int s = idx >> 4, i = idx & 15;
        size_t ro = (size_t)(base + s * step) * N3 + h * 32;
        *(unsigned*)&qs[wv][s][2 * i] = *(const unsigned*)(qkv + ro + 2 * i);
        *(unsigned*)&ks[wv][s][2 * i] = *(const unsigned*)(qkv + ro + 512 + 2 * i);
        unsigned vp = *(const unsigned*)(qkv + ro + 1024 + 2 * i);
        vT[wv][2 * i][s]     = (unsigned short)vp;
        vT[wv][2 * i + 1][s] = (unsigned short)(vp >> 16);
    }
    for (int idx = lane; idx < 32 * 19; idx += 64) {
        int d = idx / 19, k = 13 + idx % 19;
        vT[wv][d][k] = 0;
    }
    for (int idx = lane; idx < 16 * 16; idx += 64)
        pb[wv][idx >> 4][16 + (idx & 15)] = 0;
    __syncthreads();

    const int lm = lane & 15, ko = (lane >> 4) * 8, q4 = (lane >> 4) * 4;
    f32x4 zero = {0.f, 0.f, 0.f, 0.f};
    bf16x8 aq = *(const bf16x8*)&qs[wv][lm][ko];
    bf16x8 bk = *(const bf16x8*)&ks[wv][lm][ko];
    f32x4 c = __builtin_amdgcn_mfma_f32_16x16x32_bf16(aq, bk, zero, 0, 0, 0);
    const float SCALE = 0.17677669529663689f;
    float cf[4], mr[4], sm[4];
    bool colok = (lm < 13);
    #pragma unroll
    for (int r = 0; r < 4; ++r) {
        cf[r] = colok ? c[r] * SCALE : -1e30f;
        mr[r] = cf[r];
    }
    #pragma unroll
    for (int r = 0; r < 4; ++r)
        #pragma unroll
        for (int off = 1; off < 16; off <<= 1)
            mr[r] = fmaxf(mr[r], __shfl_xor(mr[r], off, 64));
    #pragma unroll
    for (int r = 0; r < 4; ++r) { cf[r] = __expf(cf[r] - mr[r]); sm[r] = cf[r]; }
    #pragma unroll
    for (int r = 0; r < 4; ++r) {
        #pragma unroll
        for (int off = 1; off < 16; off <<= 1)
            sm[r] += __shfl_xor(sm[r], off, 64);
        sm[r] = 1.f / sm[r];
    }
    #pragma unroll
    for (int r = 0; r < 4; ++r)
        pb[wv][q4 + r][lm] = f2bf(cf[r] * sm[r]);
    __builtin_amdgcn_wave_barrier();
    bf16x8 ap  = *(const bf16x8*)&pb[wv][lm][ko];
    bf16x8 vf0 = *(const bf16x8*)&vT[wv][lm][ko];
    bf16x8 vf1 = *(const bf16x8*)&vT[wv][16 + lm][ko];
    f32x4 o0 = __builtin_amdgcn_mfma_f32_16x16x32_bf16(ap, vf0, zero, 0, 0, 0);
    f32x4 o1 = __builtin_amdgcn_mfma_f32_16x16x32_bf16(ap, vf1, zero, 0, 0, 0);
    #pragma unroll
    for (int r = 0; r < 4; ++r) {
        int row = q4 + r;
        if (row < 13) {
            size_t ro = (size_t)(base + row * step) * N3 + h * 32;
            qkv[ro + lm]      = f2bf(o0[r]);
            qkv[ro + 16 + lm] = f2bf(o1[r]);
        }
    }
}

// ---------------------------------------------------------------- launch
extern "C" void kernel_launch(void* const* d_in, const int* in_sizes, int n_in,
                              void* d_out, int out_size, void* d_ws, size_t ws_size,
                              hipStream_t stream) {
    const float* x        = (const float*)d_in[0];
    const float* lat_grid = (const float*)d_in[1];
    const float* lon_grid = (const float*)d_in[2];
    const float* qkv_w[3] = {(const float*)d_in[3], (const float*)d_in[5], (const float*)d_in[7]};
    const float* qkv_b[3] = {(const float*)d_in[4], (const float*)d_in[6], (const float*)d_in[8]};
    const float* proj_w   = (const float*)d_in[9];
    const float* proj_b   = (const float*)d_in[10];
    const float* g[3]     = {(const float*)d_in[11], (const float*)d_in[13], (const float*)d_in[15]};
    const float* bln[3]   = {(const float*)d_in[12], (const float*)d_in[14], (const float*)d_in[16]};
    float* tok = (float*)d_out;

    unsigned short* wT0 = (unsigned short*)d_ws;
    unsigned short* wT1 = wT0 + 1536 * 512;
    unsigned short* wT2 = wT1 + 1536 * 512;
    unsigned short* pT  = wT2 + 1536 * 512;
    unsigned short* lnb = pT + 512 * 512;
    unsigned short* qkv = lnb + (size_t)MTOK * 512;
    unsigned short* wT[3] = {wT0, wT1, wT2};

    transpose_w<<<dim3(8, 24), 256, 0, stream>>>(qkv_w[0], wT0, 1536);
    transpose_w<<<dim3(8, 24), 256, 0, stream>>>(qkv_w[1], wT1, 1536);
    transpose_w<<<dim3(8, 24), 256, 0, stream>>>(qkv_w[2], wT2, 1536);
    transpose_w<<<dim3(8, 8),  256, 0, stream>>>(proj_w, pT, 512);

    for (int b = 0; b < 3; ++b) {
        const float* src = (b == 0) ? x : tok;
        ln_apply<<<MTOK / 4, 256, 0, stream>>>(src, g[b], bln[b], lnb);
        gemm8p<512, 6, false><<<dim3(6, MTOK / 256), 512, 0, stream>>>(
            lnb, wT[b], qkv_b[b], nullptr, nullptr, qkv);
        if (b == 0)
            attn_big<48, 0><<<dim3(L_DIM * W_DIM, NH), 256, 0, stream>>>(qkv, lat_grid, lon_grid);
        else if (b == 1)
            attn_big<96, 1><<<dim3(L_DIM * H_DIM, NH), 256, 0, stream>>>(qkv, lat_grid, lon_grid);
        else
            attn_small<<<(H_DIM * W_DIM * NH) / 4, 256, 0, stream>>>(qkv);
        gemm8p<1536, 2, true><<<dim3(2, MTOK / 256), 512, 0, stream>>>(
            qkv, pT, proj_b, src, tok, nullptr);
    }
}

// Round 2
// 1253.743 us; speedup vs baseline: 1.0106x; 1.0106x over previous
//
#include <hip/hip_runtime.h>
#include <cstdint>

// AxialAttention3D on MI355X.
// Tokens live fp32 in d_out, layout (L=13, H=48, W=96, D=512), updated in place
// by each of the three axial blocks. Workspace (all ushort):
//   wT[3] : qkv weights transposed to (N=1536, K=512) bf16   3 x 1.5 MB
//   pT    : proj weight transposed to (512,512) bf16         0.5 MB
//   lnb   : LN(tok) bf16 (59904, 512)                        61 MB
//   qkv   : (59904, 1536) bf16                               184 MB
// GEMMs: 256x256 tile, BK=64, 8 waves (2Mx4N), 4 SEPARATE 32KB LDS buffers
// (distinct objects -> NoAlias -> backend keeps counted vmcnt instead of
// inserting vmcnt(0) drains between global_load_lds and ds_read), K-loop
// rolled over tile PAIRS with literal buffer refs, counted vmcnt (never 0
// mid-loop), setprio around MFMA, XOR-granule swizzled staging, bijective
// XCD tile swizzle. MFMA operands swapped (mfma(B,A)) so lane's acc quad is
// 4 consecutive output COLUMNS -> packed 8B bf16 / float4 resid stores.

#define L_DIM 13
#define H_DIM 48
#define W_DIM 96
#define D_DIM 512
#define NH    16
#define MTOK  (L_DIM * H_DIM * W_DIM)   // 59904
#define N3    (3 * D_DIM)               // 1536
#define PI_F  3.14159265358979323846f

typedef __bf16 bf16x8 __attribute__((ext_vector_type(8)));
typedef float  f32x4  __attribute__((ext_vector_type(4)));

__device__ __forceinline__ float bf2f(unsigned short u) {
    return __builtin_bit_cast(float, ((unsigned)u) << 16);
}
__device__ __forceinline__ unsigned short f2bf(float f) {
    unsigned u = __builtin_bit_cast(unsigned, f);
    u += 0x7fffu + ((u >> 16) & 1u);   // round-to-nearest-even
    return (unsigned short)(u >> 16);
}
// async global->LDS, 16B per lane; lds dest = wave-uniform base + lane*16
__device__ __forceinline__ void gload16(unsigned short* lds, const unsigned short* g) {
    __builtin_amdgcn_global_load_lds(
        (const __attribute__((address_space(1))) unsigned int*)g,
        (__attribute__((address_space(3))) unsigned int*)lds, 16, 0, 0);
}

// ---------------------------------------------------------------- W (512 x N) -> W^T (N x 512) bf16
__global__ __launch_bounds__(256) void transpose_w(const float* __restrict__ w,
                                                   unsigned short* __restrict__ wt, int N) {
    __shared__ unsigned short t[64][65];
    const int k0 = blockIdx.x * 64, n0 = blockIdx.y * 64;
    const int tid = threadIdx.x;
    #pragma unroll
    for (int j = 0; j < 16; ++j) {
        int lin = j * 256 + tid;
        int kr = lin >> 6, nc = lin & 63;
        t[kr][nc] = f2bf(w[(size_t)(k0 + kr) * N + n0 + nc]);
    }
    __syncthreads();
    #pragma unroll
    for (int j = 0; j < 16; ++j) {
        int lin = j * 256 + tid;
        int nr = lin >> 6, kc = lin & 63;
        wt[(size_t)(n0 + nr) * 512 + k0 + kc] = t[kc][nr];
    }
}

// ---------------------------------------------------------------- fused LN: src fp32 -> bf16
__global__ __launch_bounds__(256) void ln_apply(
    const float* __restrict__ src, const float* __restrict__ g,
    const float* __restrict__ bln, unsigned short* __restrict__ out)
{
    int wv = threadIdx.x >> 6, lane = threadIdx.x & 63;
    int t = blockIdx.x * 4 + wv;
    const float* p = src + (size_t)t * 512 + lane * 8;
    float4 a = *(const float4*)p, b = *(const float4*)(p + 4);
    float s  = a.x + a.y + a.z + a.w + b.x + b.y + b.z + b.w;
    float s2 = a.x*a.x + a.y*a.y + a.z*a.z + a.w*a.w + b.x*b.x + b.y*b.y + b.z*b.z + b.w*b.w;
    #pragma unroll
    for (int off = 1; off < 64; off <<= 1) {
        s  += __shfl_xor(s, off, 64);
        s2 += __shfl_xor(s2, off, 64);
    }
    float mu = s * (1.f / 512.f);
    float rs = rsqrtf(s2 * (1.f / 512.f) - mu * mu + 1e-5f);
    float4 g0 = *(const float4*)(g + lane * 8),  g1 = *(const float4*)(g + lane * 8 + 4);
    float4 b0 = *(const float4*)(bln + lane * 8), b1 = *(const float4*)(bln + lane * 8 + 4);
    unsigned short o[8];
    o[0] = f2bf((a.x - mu) * rs * g0.x + b0.x);
    o[1] = f2bf((a.y - mu) * rs * g0.y + b0.y);
    o[2] = f2bf((a.z - mu) * rs * g0.z + b0.z);
    o[3] = f2bf((a.w - mu) * rs * g0.w + b0.w);
    o[4] = f2bf((b.x - mu) * rs * g1.x + b1.x);
    o[5] = f2bf((b.y - mu) * rs * g1.y + b1.y);
    o[6] = f2bf((b.z - mu) * rs * g1.z + b1.z);
    o[7] = f2bf((b.w - mu) * rs * g1.w + b1.w);
    uint4 r;
    r.x = (unsigned)o[0] | ((unsigned)o[1] << 16);
    r.y = (unsigned)o[2] | ((unsigned)o[3] << 16);
    r.z = (unsigned)o[4] | ((unsigned)o[5] << 16);
    r.w = (unsigned)o[6] | ((unsigned)o[7] << 16);
    *(uint4*)&out[(size_t)t * 512 + lane * 8] = r;
}

// ---------------------------------------------------------------- 256x256 8-phase GEMM
// C(M x N) = A(M x K=512, row stride LDA) * B^T (B is N x 512 row-major) + bias
// !PROJ: outh bf16, row stride N3.  PROJ: outf fp32 = resid + C + bias, stride 512.
// Staging ledger per wave per K-tile: SB(4 loads)@q0, SA0(2)@q1, SA1(2)@q2.
// Waits: end-q0 vmcnt(4) [SA1(t) done], end-q3 vmcnt(2) [SB,SA0(t+1) done].
#define QUAD(mi, A) do { \
    acc[mi][0] = __builtin_amdgcn_mfma_f32_16x16x32_bf16(b0, A, acc[mi][0], 0, 0, 0); \
    acc[mi][1] = __builtin_amdgcn_mfma_f32_16x16x32_bf16(b1, A, acc[mi][1], 0, 0, 0); \
    acc[mi][2] = __builtin_amdgcn_mfma_f32_16x16x32_bf16(b2, A, acc[mi][2], 0, 0, 0); \
    acc[mi][3] = __builtin_amdgcn_mfma_f32_16x16x32_bf16(b3, A, acc[mi][3], 0, 0, 0); \
} while (0)
#define RDA(AS, mi, ks) (*(const bf16x8*)&AS[wm + (mi) * 16 + lm][((((ks) * 4 + kq) ^ (lm & 7)) << 3)])
#define RDB(BS, ni, ks) (*(const bf16x8*)&BS[wn + (ni) * 16 + lm][((((ks) * 4 + kq) ^ (lm & 7)) << 3)])

// One K-tile: read CAs/CBs, stage NAs/NBs (ST compile-time). 4 phases, 2 barriers each.
#define KTILE(CAs, CBs, NAs, NBs, kn, ST, LAST) do {                               \
    bf16x8 a0, a1, a2, a3, b0, b1, b2, b3;                                         \
    /* q0: mi 0-3 x ks0; stage SB(t+1) */                                          \
    a0 = RDA(CAs,0,0); a1 = RDA(CAs,1,0); a2 = RDA(CAs,2,0); a3 = RDA(CAs,3,0);    \
    b0 = RDB(CBs,0,0); b1 = RDB(CBs,1,0); b2 = RDB(CBs,2,0); b3 = RDB(CBs,3,0);    \
    if (ST) {                                                                      \
        gload16(&NBs[wv * 32 +  0][0], bsrc + (size_t) 0 * 512 + (kn));            \
        gload16(&NBs[wv * 32 +  8][0], bsrc + (size_t) 8 * 512 + (kn));            \
        gload16(&NBs[wv * 32 + 16][0], bsrc + (size_t)16 * 512 + (kn));            \
        gload16(&NBs[wv * 32 + 24][0], bsrc + (size_t)24 * 512 + (kn));            \
    }                                                                              \
    __builtin_amdgcn_s_barrier();                                                  \
    __builtin_amdgcn_s_setprio(1);                                                 \
    QUAD(0, a0); QUAD(1, a1); QUAD(2, a2); QUAD(3, a3);                            \
    __builtin_amdgcn_s_setprio(0);                                                 \
    if (ST) asm volatile("s_waitcnt vmcnt(4)" ::: "memory");  /* SA1(t) landed */  \
    else    asm volatile("s_waitcnt vmcnt(0)" ::: "memory");  /* tail drain */     \
    __builtin_amdgcn_s_barrier();                                                  \
    __builtin_amdgcn_sched_barrier(0);                                             \
    /* q1: mi 4-7 x ks0 (B regs reused); stage SA0(t+1) */                         \
    a0 = RDA(CAs,4,0); a1 = RDA(CAs,5,0); a2 = RDA(CAs,6,0); a3 = RDA(CAs,7,0);    \
    if (ST) {                                                                      \
        gload16(&NAs[ar0 + 0][0], asrc + (kn));                                    \
        gload16(&NAs[ar0 + 8][0], asrc + (size_t)8 * LDA + (kn));                  \
    }                                                                              \
    __builtin_amdgcn_s_barrier();                                                  \
    __builtin_amdgcn_s_setprio(1);                                                 \
    QUAD(4, a0); QUAD(5, a1); QUAD(6, a2); QUAD(7, a3);                            \
    __builtin_amdgcn_s_setprio(0);                                                 \
    __builtin_amdgcn_s_barrier();                                                  \
    /* q2: mi 0-3 x ks1; stage SA1(t+1) */                                         \
    a0 = RDA(CAs,0,1); a1 = RDA(CAs,1,1); a2 = RDA(CAs,2,1); a3 = RDA(CAs,3,1);    \
    b0 = RDB(CBs,0,1); b1 = RDB(CBs,1,1); b2 = RDB(CBs,2,1); b3 = RDB(CBs,3,1);    \
    if (ST) {                                                                      \
        gload16(&NAs[ar0 + 64][0], asrc + (size_t)64 * LDA + (kn));                \
        gload16(&NAs[ar0 + 72][0], asrc + (size_t)72 * LDA + (kn));                \
    }                                                                              \
    __builtin_amdgcn_s_barrier();                                                  \
    __builtin_amdgcn_s_setprio(1);                                                 \
    QUAD(0, a0); QUAD(1, a1); QUAD(2, a2); QUAD(3, a3);                            \
    __builtin_amdgcn_s_setprio(0);                                                 \
    __builtin_amdgcn_s_barrier();                                                  \
    /* q3: mi 4-7 x ks1 */                                                         \
    a0 = RDA(CAs,4,1); a1 = RDA(CAs,5,1); a2 = RDA(CAs,6,1); a3 = RDA(CAs,7,1);    \
    __builtin_amdgcn_s_barrier();                                                  \
    __builtin_amdgcn_s_setprio(1);                                                 \
    QUAD(4, a0); QUAD(5, a1); QUAD(6, a2); QUAD(7, a3);                            \
    __builtin_amdgcn_s_setprio(0);                                                 \
    if (ST) asm volatile("s_waitcnt vmcnt(2)" ::: "memory"); /* SB,SA0(t+1) in */  \
    if (!LAST) __builtin_amdgcn_s_barrier();                                       \
    __builtin_amdgcn_sched_barrier(0);                                             \
} while (0)

template<int LDA, int NBX, bool PROJ>
__global__ __launch_bounds__(512, 2) void gemm8p(
    const unsigned short* __restrict__ A,
    const unsigned short* __restrict__ B,
    const float* __restrict__ bias,
    const float* __restrict__ resid,
    float* __restrict__ outf,
    unsigned short* __restrict__ outh)
{
    // four DISTINCT objects: NoAlias between read-buffer ds_read and
    // in-flight global_load_lds DMA into the write buffer.
    __shared__ alignas(16) unsigned short As0[256][64];
    __shared__ alignas(16) unsigned short As1[256][64];
    __shared__ alignas(16) unsigned short Bs0[256][64];
    __shared__ alignas(16) unsigned short Bs1[256][64];

    // bijective XCD swizzle (m204): contiguous tile chunk per XCD
    const int nwg = NBX * 234;
    const int orig = blockIdx.y * NBX + blockIdx.x;
    const int qq = nwg >> 3, rr = nwg & 7;
    const int xcd = orig & 7, idx = orig >> 3;
    const int swz = (xcd < rr ? xcd * (qq + 1) : rr * (qq + 1) + (xcd - rr) * qq) + idx;
    const int n0 = (swz % NBX) * 256;
    const int m0 = (swz / NBX) * 256;

    const int tid = threadIdx.x, lane = tid & 63, wv = tid >> 6;
    const int wm = (wv >> 2) * 128, wn = (wv & 3) * 64;
    const int lm = lane & 15, kq = lane >> 4;
    const int rblk = lane >> 3;
    const int sc = (((lane & 7) ^ rblk) << 3);          // pre-swizzled source granule

    // staging source bases (per lane)
    const unsigned short* bsrc = B + (size_t)(n0 + wv * 32 + rblk) * 512 + sc;
    const int ar0 = (wv & 4) ? (128 + (wv & 3) * 16) : (wv * 16);  // rows for q0/q2
    const unsigned short* asrc = A + (size_t)(m0 + ar0 + rblk) * LDA + sc;

    f32x4 acc[8][4] = {};

    // prologue: stage K-tile 0 into buffer 0
    #pragma unroll
    for (int j = 0; j < 4; ++j)
        gload16(&Bs0[wv * 32 + j * 8][0], bsrc + (size_t)(j * 8) * 512);
    gload16(&As0[ar0 + 0][0], asrc);
    gload16(&As0[ar0 + 8][0], asrc + (size_t)8 * LDA);
    gload16(&As0[ar0 + 64][0], asrc + (size_t)64 * LDA);
    gload16(&As0[ar0 + 72][0], asrc + (size_t)72 * LDA);
    asm volatile("s_waitcnt vmcnt(2)" ::: "memory");    // SB(0)+SA0(0) done
    __builtin_amdgcn_s_barrier();
    __builtin_amdgcn_sched_barrier(0);

    // tiles 0..5: rolled pairs with literal buffer refs
    for (int kt = 0; kt < 6; kt += 2) {
        KTILE(As0, Bs0, As1, Bs1, (kt + 1) * 64, true, false);
        KTILE(As1, Bs1, As0, Bs0, (kt + 2) * 64, true, false);
    }
    // tiles 6,7 peeled (tail staging/no-staging compile-time)
    KTILE(As0, Bs0, As1, Bs1, 7 * 64, true, false);
    KTILE(As1, Bs1, As0, Bs0, 0, false, true);

    // epilogue: swapped operands -> lane holds 4 consecutive COLS of row (wm+mi*16+lm)
    const int cr = kq << 2;
    if constexpr (!PROJ) {
        #pragma unroll
        for (int ni = 0; ni < 4; ++ni) {
            const int col = n0 + wn + ni * 16 + cr;
            const float4 bb = *(const float4*)&bias[col];
            #pragma unroll
            for (int mi = 0; mi < 8; ++mi) {
                const size_t off = (size_t)(m0 + wm + mi * 16 + lm) * N3 + col;
                uint2 pk;
                pk.x = (unsigned)f2bf(acc[mi][ni][0] + bb.x) | ((unsigned)f2bf(acc[mi][ni][1] + bb.y) << 16);
                pk.y = (unsigned)f2bf(acc[mi][ni][2] + bb.z) | ((unsigned)f2bf(acc[mi][ni][3] + bb.w) << 16);
                *(uint2*)&outh[off] = pk;
            }
        }
    } else {
        #pragma unroll
        for (int ni = 0; ni < 4; ++ni) {
            const int col = n0 + wn + ni * 16 + cr;
            const float4 bb = *(const float4*)&bias[col];
            #pragma unroll
            for (int mi = 0; mi < 8; ++mi) {
                const size_t off = (size_t)(m0 + wm + mi * 16 + lm) * 512 + col;
                float4 rs = *(const float4*)&resid[off];
                float4 o;
                o.x = rs.x + acc[mi][ni][0] + bb.x;
                o.y = rs.y + acc[mi][ni][1] + bb.y;
                o.z = rs.z + acc[mi][ni][2] + bb.z;
                o.w = rs.w + acc[mi][ni][3] + bb.w;
                *(float4*)&outf[off] = o;      // resid may alias outf (same element)
            }
        }
    }
}

// ---------------------------------------------------------------- MFMA attention, S in {48, 96}
template<int S, int MODE>
__global__ __launch_bounds__(256) void attn_big(
    unsigned short* __restrict__ qkv,
    const float* __restrict__ lat_grid, const float* __restrict__ lon_grid)
{
    constexpr int NQ  = S / 16;
    constexpr int SKP = (S + 31) & ~31;
    constexpr int VST = SKP + 8;
    __shared__ alignas(16) unsigned short qs[S][40];
    __shared__ alignas(16) unsigned short ks[S][40];
    __shared__ alignas(16) unsigned short vT[32][VST];
    __shared__ alignas(16) unsigned short pb[4][16][VST];

    const int n = blockIdx.x, h = blockIdx.y;
    const int tid = threadIdx.x, lane = tid & 63, wv = tid >> 6;
    int base, step;
    if (MODE == 0) { int l = n / 96, w = n - l * 96; base = l * 4608 + w; step = 96; }
    else           { base = n * 96; step = 1; }

    const float SCALE = 0.17677669529663689f;   // 1/sqrt(32)
    for (int idx = tid; idx < S * 16; idx += 256) {
        int s = idx >> 4, i = idx & 15;
        size_t ro = (size_t)(base + s * step) * N3 + h * 32;
        unsigned qp = *(const unsigned*)(qkv + ro + 2 * i);
        unsigned kp = *(const unsigned*)(qkv + ro + 512 + 2 * i);
        unsigned vp = *(const unsigned*)(qkv + ro + 1024 + 2 * i);
        float coord;
        if (MODE == 0) {
            float la = lat_grid[s];
            coord = fminf(fmaxf(la, -PI_F / 2 + 1e-6f), PI_F / 2 - 1e-6f);
        } else {
            float xp = lon_grid[s] + PI_F;
            coord = xp - floorf(xp * (0.5f / PI_F)) * (2.f * PI_F) - PI_F;
        }
        float ph = coord * exp2f(-(float)i * 0.83048202372f); // log2(1e4)/16
        float sn = sinf(ph), cs = cosf(ph);
        float q1 = bf2f((unsigned short)qp), q2 = bf2f((unsigned short)(qp >> 16));
        float k1 = bf2f((unsigned short)kp), k2 = bf2f((unsigned short)(kp >> 16));
        qs[s][i]      = f2bf((q1 * cs - q2 * sn) * SCALE);
        qs[s][16 + i] = f2bf((q1 * sn + q2 * cs) * SCALE);
        ks[s][i]      = f2bf(k1 * cs - k2 * sn);
        ks[s][16 + i] = f2bf(k1 * sn + k2 * cs);
        vT[2 * i][s]     = (unsigned short)vp;
        vT[2 * i + 1][s] = (unsigned short)(vp >> 16);
    }
    if (SKP > S) {
        for (int idx = tid; idx < 32 * (SKP - S); idx += 256)
            vT[idx / (SKP - S)][S + idx % (SKP - S)] = 0;
    }
    __syncthreads();

    const int lm = lane & 15, ko = (lane >> 4) * 8, q4 = (lane >> 4) * 4;
    f32x4 zero = {0.f, 0.f, 0.f, 0.f};
    bf16x8 vf[SKP / 32][2];
    #pragma unroll
    for (int u2 = 0; u2 < SKP / 32; ++u2)
        #pragma unroll
        for (int nh2 = 0; nh2 < 2; ++nh2)
            vf[u2][nh2] = *(const bf16x8*)&vT[nh2 * 16 + lm][u2 * 32 + ko];
    if (SKP > S) {
        for (int idx = lane; idx < 16 * (SKP - S); idx += 64)
            pb[wv][idx / (SKP - S)][S + idx % (SKP - S)] = 0;
    }

    for (int t = wv; t < NQ; t += 4) {
        bf16x8 aq = *(const bf16x8*)&qs[t * 16 + lm][ko];
        f32x4 c[NQ];
        #pragma unroll
        for (int u = 0; u < NQ; ++u) {
            bf16x8 bk = *(const bf16x8*)&ks[u * 16 + lm][ko];
            c[u] = __builtin_amdgcn_mfma_f32_16x16x32_bf16(aq, bk, zero, 0, 0, 0);
        }
        float mr[4] = {-1e30f, -1e30f, -1e30f, -1e30f}, sm[4] = {0.f, 0.f, 0.f, 0.f};
        #pragma unroll
        for (int u = 0; u < NQ; ++u)
            #pragma unroll
            for (int r = 0; r < 4; ++r) mr[r] = fmaxf(mr[r], c[u][r]);
        #pragma unroll
        for (int r = 0; r < 4; ++r)
            #pragma unroll
            for (int off = 1; off < 16; off <<= 1)
                mr[r] = fmaxf(mr[r], __shfl_xor(mr[r], off, 64));
        #pragma unroll
        for (int u = 0; u < NQ; ++u)
            #pragma unroll
            for (int r = 0; r < 4; ++r) {
                float e = __expf(c[u][r] - mr[r]);
                c[u][r] = e; sm[r] += e;
            }
        #pragma unroll
        for (int r = 0; r < 4; ++r) {
            #pragma unroll
            for (int off = 1; off < 16; off <<= 1)
                sm[r] += __shfl_xor(sm[r], off, 64);
            sm[r] = 1.f / sm[r];
        }
        #pragma unroll
        for (int u = 0; u < NQ; ++u)
            #pragma unroll
            for (int r = 0; r < 4; ++r)
                pb[wv][q4 + r][u * 16 + lm] = f2bf(c[u][r] * sm[r]);
        __builtin_amdgcn_wave_barrier();
        f32x4 o0 = zero, o1 = zero;
        #pragma unroll
        for (int u2 = 0; u2 < SKP / 32; ++u2) {
            bf16x8 ap = *(const bf16x8*)&pb[wv][lm][u2 * 32 + ko];
            o0 = __builtin_amdgcn_mfma_f32_16x16x32_bf16(ap, vf[u2][0], o0, 0, 0, 0);
            o1 = __builtin_amdgcn_mfma_f32_16x16x32_bf16(ap, vf[u2][1], o1, 0, 0, 0);
        }
        __builtin_amdgcn_wave_barrier();
        #pragma unroll
        for (int r = 0; r < 4; ++r) {
            int row = t * 16 + q4 + r;
            size_t ro = (size_t)(base + row * step) * N3 + h * 32;
            qkv[ro + lm]      = f2bf(o0[r]);
            qkv[ro + 16 + lm] = f2bf(o1[r]);
        }
    }
}

// ---------------------------------------------------------------- MFMA attention, S=13 (lev)
__global__ __launch_bounds__(256) void attn_small(unsigned short* __restrict__ qkv)
{
    __shared__ alignas(16) unsigned short qs[4][16][40];
    __shared__ alignas(16) unsigned short ks[4][16][40];
    __shared__ alignas(16) unsigned short vT[4][32][40];
    __shared__ alignas(16) unsigned short pb[4][16][40];
    const int tid = threadIdx.x, lane = tid & 63, wv = tid >> 6;
    const int pair = blockIdx.x * 4 + wv;
    const int n = pair >> 4, h = pair & 15;
    const int base = n, step = 4608;

    for (int idx = lane; idx < 13 * 16; idx += 64) {
        int s = idx >> 4, i = idx & 15;
        size_t ro = (size_t)(base + s * step) * N3 + h * 32;
        *(unsigned*)&qs[wv][s][2 * i] = *(const unsigned*)(qkv + ro + 2 * i);
        *(unsigned*)&ks[wv][s][2 * i] = *(const unsigned*)(qkv + ro + 512 + 2 * i);
        unsigned vp = *(const unsigned*)(qkv + ro + 1024 + 2 * i);
        vT[wv][2 * i][s]     = (unsigned short)vp;
        vT[wv][2 * i + 1][s] = (unsigned short)(vp >> 16);
    }
    for (int idx = lane; idx < 32 * 19; idx += 64) {
        int d = idx / 19, k = 13 + idx % 19;
        vT[wv][d][k] = 0;
    }
    for (int idx = lane; idx < 16 * 16; idx += 64)
        pb[wv][idx >> 4][16 + (idx & 15)] = 0;
    __syncthreads();

    const int lm = lane & 15, ko = (lane >> 4) * 8, q4 = (lane >> 4) * 4;
    f32x4 zero = {0.f, 0.f, 0.f, 0.f};
    bf16x8 aq = *(const bf16x8*)&qs[wv][lm][ko];
    bf16x8 bk = *(const bf16x8*)&ks[wv][lm][ko];
    f32x4 c = __builtin_amdgcn_mfma_f32_16x16x32_bf16(aq, bk, zero, 0, 0, 0);
    const float SCALE = 0.17677669529663689f;
    float cf[4], mr[4], sm[4];
    bool colok = (lm < 13);
    #pragma unroll
    for (int r = 0; r < 4; ++r) {
        cf[r] = colok ? c[r] * SCALE : -1e30f;
        mr[r] = cf[r];
    }
    #pragma unroll
    for (int r = 0; r < 4; ++r)
        #pragma unroll
        for (int off = 1; off < 16; off <<= 1)
            mr[r] = fmaxf(mr[r], __shfl_xor(mr[r], off, 64));
    #pragma unroll
    for (int r = 0; r < 4; ++r) { cf[r] = __expf(cf[r] - mr[r]); sm[r] = cf[r]; }
    #pragma unroll
    for (int r = 0; r < 4; ++r) {
        #pragma unroll
        for (int off = 1; off < 16; off <<= 1)
            sm[r] += __shfl_xor(sm[r], off, 64);
        sm[r] = 1.f / sm[r];
    }
    #pragma unroll
    for (int r = 0; r < 4; ++r)
        pb[wv][q4 + r][lm] = f2bf(cf[r] * sm[r]);
    __builtin_amdgcn_wave_barrier();
    bf16x8 ap  = *(const bf16x8*)&pb[wv][lm][ko];
    bf16x8 vf0 = *(const bf16x8*)&vT[wv][lm][ko];
    bf16x8 vf1 = *(const bf16x8*)&vT[wv][16 + lm][ko];
    f32x4 o0 = __builtin_amdgcn_mfma_f32_16x16x32_bf16(ap, vf0, zero, 0, 0, 0);
    f32x4 o1 = __builtin_amdgcn_mfma_f32_16x16x32_bf16(ap, vf1, zero, 0, 0, 0);
    #pragma unroll
    for (int r = 0; r < 4; ++r) {
        int row = q4 + r;
        if (row < 13) {
            size_t ro = (size_t)(base + row * step) * N3 + h * 32;
            qkv[ro + lm]      = f2bf(o0[r]);
            qkv[ro + 16 + lm] = f2bf(o1[r]);
        }
    }
}

// ---------------------------------------------------------------- launch
extern "C" void kernel_launch(void* const* d_in, const int* in_sizes, int n_in,
                              void* d_out, int out_size, void* d_ws, size_t ws_size,
                              hipStream_t stream) {
    const float* x        = (const float*)d_in[0];
    const float* lat_grid = (const float*)d_in[1];
    const float* lon_grid = (const float*)d_in[2];
    const float* qkv_w[3] = {(const float*)d_in[3], (const float*)d_in[5], (const float*)d_in[7]};
    const float* qkv_b[3] = {(const float*)d_in[4], (const float*)d_in[6], (const float*)d_in[8]};
    const float* proj_w   = (const float*)d_in[9];
    const float* proj_b   = (const float*)d_in[10];
    const float* g[3]     = {(const float*)d_in[11], (const float*)d_in[13], (const float*)d_in[15]};
    const float* bln[3]   = {(const float*)d_in[12], (const float*)d_in[14], (const float*)d_in[16]};
    float* tok = (float*)d_out;

    unsigned short* wT0 = (unsigned short*)d_ws;
    unsigned short* wT1 = wT0 + 1536 * 512;
    unsigned short* wT2 = wT1 + 1536 * 512;
    unsigned short* pT  = wT2 + 1536 * 512;
    unsigned short* lnb = pT + 512 * 512;
    unsigned short* qkv = lnb + (size_t)MTOK * 512;
    unsigned short* wT[3] = {wT0, wT1, wT2};

    transpose_w<<<dim3(8, 24), 256, 0, stream>>>(qkv_w[0], wT0, 1536);
    transpose_w<<<dim3(8, 24), 256, 0, stream>>>(qkv_w[1], wT1, 1536);
    transpose_w<<<dim3(8, 24), 256, 0, stream>>>(qkv_w[2], wT2, 1536);
    transpose_w<<<dim3(8, 8),  256, 0, stream>>>(proj_w, pT, 512);

    for (int b = 0; b < 3; ++b) {
        const float* src = (b == 0) ? x : tok;
        ln_apply<<<MTOK / 4, 256, 0, stream>>>(src, g[b], bln[b], lnb);
        gemm8p<512, 6, false><<<dim3(6, MTOK / 256), 512, 0, stream>>>(
            lnb, wT[b], qkv_b[b], nullptr, nullptr, qkv);
        if (b == 0)
            attn_big<48, 0><<<dim3(L_DIM * W_DIM, NH), 256, 0, stream>>>(qkv, lat_grid, lon_grid);
        else if (b == 1)
            attn_big<96, 1><<<dim3(L_DIM * H_DIM, NH), 256, 0, stream>>>(qkv, lat_grid, lon_grid);
        else
            attn_small<<<(H_DIM * W_DIM * NH) / 4, 256, 0, stream>>>(qkv);
        gemm8p<1536, 2, true><<<dim3(2, MTOK / 256), 512, 0, stream>>>(
            qkv, pT, proj_b, src, tok, nullptr);
    }
}

// Round 3
// 1235.991 us; speedup vs baseline: 1.0251x; 1.0144x over previous
//
#include <hip/hip_runtime.h>
#include <cstdint>

// AxialAttention3D on MI355X.
// Tokens live fp32 in d_out, layout (L=13, H=48, W=96, D=512), updated in place
// by each of the three axial blocks. Workspace (all ushort):
//   wT[3] : qkv weights transposed to (N=1536, K=512) bf16   3 x 1.5 MB
//   pT    : proj weight transposed to (512,512) bf16         0.5 MB
//   lnb   : LN(tok) bf16 (59904, 512)                        61 MB
//   qkv   : (59904, 1536) bf16                               184 MB
// GEMMs: 256x256 tile, BK=64, 8 waves (2Mx4N), 4 separate 32KB LDS buffers,
// FREE-RUNNING K-tile: no mid-tile barriers; all 8 staging gloads issued at
// tile start (3.5 phases of slack to the tile-end vmcnt(0)); ds_reads issued
// one MFMA-group ahead in pinned program order (sched_barrier(0) fences) so
// the compiler emits counted lgkmcnt waits; ONE vmcnt(0)+s_barrier per K-tile
// for cross-wave staging visibility + WAR. setprio around MFMA clusters,
// XOR-granule swizzled staging, bijective XCD tile swizzle. MFMA operands
// swapped (mfma(B,A)) so lane's acc quad is 4 consecutive output COLUMNS ->
// packed 8B bf16 / float4 resid stores.

#define L_DIM 13
#define H_DIM 48
#define W_DIM 96
#define D_DIM 512
#define NH    16
#define MTOK  (L_DIM * H_DIM * W_DIM)   // 59904
#define N3    (3 * D_DIM)               // 1536
#define PI_F  3.14159265358979323846f

typedef __bf16 bf16x8 __attribute__((ext_vector_type(8)));
typedef float  f32x4  __attribute__((ext_vector_type(4)));

__device__ __forceinline__ float bf2f(unsigned short u) {
    return __builtin_bit_cast(float, ((unsigned)u) << 16);
}
__device__ __forceinline__ unsigned short f2bf(float f) {
    unsigned u = __builtin_bit_cast(unsigned, f);
    u += 0x7fffu + ((u >> 16) & 1u);   // round-to-nearest-even
    return (unsigned short)(u >> 16);
}
// async global->LDS, 16B per lane; lds dest = wave-uniform base + lane*16
__device__ __forceinline__ void gload16(unsigned short* lds, const unsigned short* g) {
    __builtin_amdgcn_global_load_lds(
        (const __attribute__((address_space(1))) unsigned int*)g,
        (__attribute__((address_space(3))) unsigned int*)lds, 16, 0, 0);
}

// ---------------------------------------------------------------- W (512 x N) -> W^T (N x 512) bf16
__global__ __launch_bounds__(256) void transpose_w(const float* __restrict__ w,
                                                   unsigned short* __restrict__ wt, int N) {
    __shared__ unsigned short t[64][65];
    const int k0 = blockIdx.x * 64, n0 = blockIdx.y * 64;
    const int tid = threadIdx.x;
    #pragma unroll
    for (int j = 0; j < 16; ++j) {
        int lin = j * 256 + tid;
        int kr = lin >> 6, nc = lin & 63;
        t[kr][nc] = f2bf(w[(size_t)(k0 + kr) * N + n0 + nc]);
    }
    __syncthreads();
    #pragma unroll
    for (int j = 0; j < 16; ++j) {
        int lin = j * 256 + tid;
        int nr = lin >> 6, kc = lin & 63;
        wt[(size_t)(n0 + nr) * 512 + k0 + kc] = t[kc][nr];
    }
}

// ---------------------------------------------------------------- fused LN: src fp32 -> bf16
__global__ __launch_bounds__(256) void ln_apply(
    const float* __restrict__ src, const float* __restrict__ g,
    const float* __restrict__ bln, unsigned short* __restrict__ out)
{
    int wv = threadIdx.x >> 6, lane = threadIdx.x & 63;
    int t = blockIdx.x * 4 + wv;
    const float* p = src + (size_t)t * 512 + lane * 8;
    float4 a = *(const float4*)p, b = *(const float4*)(p + 4);
    float s  = a.x + a.y + a.z + a.w + b.x + b.y + b.z + b.w;
    float s2 = a.x*a.x + a.y*a.y + a.z*a.z + a.w*a.w + b.x*b.x + b.y*b.y + b.z*b.z + b.w*b.w;
    #pragma unroll
    for (int off = 1; off < 64; off <<= 1) {
        s  += __shfl_xor(s, off, 64);
        s2 += __shfl_xor(s2, off, 64);
    }
    float mu = s * (1.f / 512.f);
    float rs = rsqrtf(s2 * (1.f / 512.f) - mu * mu + 1e-5f);
    float4 g0 = *(const float4*)(g + lane * 8),  g1 = *(const float4*)(g + lane * 8 + 4);
    float4 b0 = *(const float4*)(bln + lane * 8), b1 = *(const float4*)(bln + lane * 8 + 4);
    unsigned short o[8];
    o[0] = f2bf((a.x - mu) * rs * g0.x + b0.x);
    o[1] = f2bf((a.y - mu) * rs * g0.y + b0.y);
    o[2] = f2bf((a.z - mu) * rs * g0.z + b0.z);
    o[3] = f2bf((a.w - mu) * rs * g0.w + b0.w);
    o[4] = f2bf((b.x - mu) * rs * g1.x + b1.x);
    o[5] = f2bf((b.y - mu) * rs * g1.y + b1.y);
    o[6] = f2bf((b.z - mu) * rs * g1.z + b1.z);
    o[7] = f2bf((b.w - mu) * rs * g1.w + b1.w);
    uint4 r;
    r.x = (unsigned)o[0] | ((unsigned)o[1] << 16);
    r.y = (unsigned)o[2] | ((unsigned)o[3] << 16);
    r.z = (unsigned)o[4] | ((unsigned)o[5] << 16);
    r.w = (unsigned)o[6] | ((unsigned)o[7] << 16);
    *(uint4*)&out[(size_t)t * 512 + lane * 8] = r;
}

// ---------------------------------------------------------------- 256x256 free-run GEMM
// C(M x N) = A(M x K=512, row stride LDA) * B^T (B is N x 512 row-major) + bias
// !PROJ: outh bf16, row stride N3.  PROJ: outf fp32 = resid + C + bias, stride 512.
#define MFMA4(mi, A, B0, B1, B2, B3) do { \
    acc[mi][0] = __builtin_amdgcn_mfma_f32_16x16x32_bf16(B0, A, acc[mi][0], 0, 0, 0); \
    acc[mi][1] = __builtin_amdgcn_mfma_f32_16x16x32_bf16(B1, A, acc[mi][1], 0, 0, 0); \
    acc[mi][2] = __builtin_amdgcn_mfma_f32_16x16x32_bf16(B2, A, acc[mi][2], 0, 0, 0); \
    acc[mi][3] = __builtin_amdgcn_mfma_f32_16x16x32_bf16(B3, A, acc[mi][3], 0, 0, 0); \
} while (0)
#define RDA(AS, mi, ks) (*(const bf16x8*)&AS[wm + (mi) * 16 + lm][((((ks) * 4 + kq) ^ (lm & 7)) << 3)])
#define RDB(BS, ni, ks) (*(const bf16x8*)&BS[wn + (ni) * 16 + lm][((((ks) * 4 + kq) ^ (lm & 7)) << 3)])
#define SBAR() __builtin_amdgcn_sched_barrier(0)

// One K-tile, free-running: stage ALL of tile t+1 up front, ds_reads issued one
// MFMA-group ahead (compiler emits counted lgkm waits), no mid-tile barriers.
// End of tile: vmcnt(0) + s_barrier (cross-wave visibility of staging + WAR).
#define KTILE(CAs, CBs, NAs, NBs, kn, ST, LAST) do {                               \
    if (ST) {                                                                      \
        gload16(&NBs[wv * 32 +  0][0], bsrc + (size_t) 0 * 512 + (kn));            \
        gload16(&NBs[wv * 32 +  8][0], bsrc + (size_t) 8 * 512 + (kn));            \
        gload16(&NBs[wv * 32 + 16][0], bsrc + (size_t)16 * 512 + (kn));            \
        gload16(&NBs[wv * 32 + 24][0], bsrc + (size_t)24 * 512 + (kn));            \
        gload16(&NAs[ar0 +  0][0], asrc + (kn));                                   \
        gload16(&NAs[ar0 +  8][0], asrc + (size_t) 8 * LDA + (kn));                \
        gload16(&NAs[ar0 + 64][0], asrc + (size_t)64 * LDA + (kn));                \
        gload16(&NAs[ar0 + 72][0], asrc + (size_t)72 * LDA + (kn));                \
    }                                                                              \
    SBAR();                                                                        \
    bf16x8 xa0 = RDA(CAs,0,0), xa1 = RDA(CAs,1,0), xa2 = RDA(CAs,2,0), xa3 = RDA(CAs,3,0); \
    bf16x8 xb0 = RDB(CBs,0,0), xb1 = RDB(CBs,1,0), xb2 = RDB(CBs,2,0), xb3 = RDB(CBs,3,0); \
    bf16x8 ya0 = RDA(CAs,4,0), ya1 = RDA(CAs,5,0), ya2 = RDA(CAs,6,0), ya3 = RDA(CAs,7,0); \
    SBAR();                                                                        \
    __builtin_amdgcn_s_setprio(1);                                                 \
    MFMA4(0, xa0, xb0, xb1, xb2, xb3); MFMA4(1, xa1, xb0, xb1, xb2, xb3);          \
    MFMA4(2, xa2, xb0, xb1, xb2, xb3); MFMA4(3, xa3, xb0, xb1, xb2, xb3);          \
    __builtin_amdgcn_s_setprio(0);                                                 \
    SBAR();                                                                        \
    bf16x8 za0 = RDA(CAs,0,1), za1 = RDA(CAs,1,1), za2 = RDA(CAs,2,1), za3 = RDA(CAs,3,1); \
    bf16x8 zb0 = RDB(CBs,0,1), zb1 = RDB(CBs,1,1), zb2 = RDB(CBs,2,1), zb3 = RDB(CBs,3,1); \
    SBAR();                                                                        \
    __builtin_amdgcn_s_setprio(1);                                                 \
    MFMA4(4, ya0, xb0, xb1, xb2, xb3); MFMA4(5, ya1, xb0, xb1, xb2, xb3);          \
    MFMA4(6, ya2, xb0, xb1, xb2, xb3); MFMA4(7, ya3, xb0, xb1, xb2, xb3);          \
    __builtin_amdgcn_s_setprio(0);                                                 \
    SBAR();                                                                        \
    bf16x8 wa0 = RDA(CAs,4,1), wa1 = RDA(CAs,5,1), wa2 = RDA(CAs,6,1), wa3 = RDA(CAs,7,1); \
    SBAR();                                                                        \
    __builtin_amdgcn_s_setprio(1);                                                 \
    MFMA4(0, za0, zb0, zb1, zb2, zb3); MFMA4(1, za1, zb0, zb1, zb2, zb3);          \
    MFMA4(2, za2, zb0, zb1, zb2, zb3); MFMA4(3, za3, zb0, zb1, zb2, zb3);          \
    __builtin_amdgcn_s_setprio(0);                                                 \
    SBAR();                                                                        \
    __builtin_amdgcn_s_setprio(1);                                                 \
    MFMA4(4, wa0, zb0, zb1, zb2, zb3); MFMA4(5, wa1, zb0, zb1, zb2, zb3);          \
    MFMA4(6, wa2, zb0, zb1, zb2, zb3); MFMA4(7, wa3, zb0, zb1, zb2, zb3);          \
    __builtin_amdgcn_s_setprio(0);                                                 \
    if (!LAST) {                                                                   \
        asm volatile("s_waitcnt vmcnt(0)" ::: "memory");                           \
        __builtin_amdgcn_s_barrier();                                              \
        SBAR();                                                                    \
    }                                                                              \
} while (0)

template<int LDA, int NBX, bool PROJ>
__global__ __launch_bounds__(512, 2) void gemm8p(
    const unsigned short* __restrict__ A,
    const unsigned short* __restrict__ B,
    const float* __restrict__ bias,
    const float* __restrict__ resid,
    float* __restrict__ outf,
    unsigned short* __restrict__ outh)
{
    // four DISTINCT objects: NoAlias between read-buffer ds_read and
    // in-flight global_load_lds DMA into the write buffer.
    __shared__ alignas(16) unsigned short As0[256][64];
    __shared__ alignas(16) unsigned short As1[256][64];
    __shared__ alignas(16) unsigned short Bs0[256][64];
    __shared__ alignas(16) unsigned short Bs1[256][64];

    // bijective XCD swizzle (m204): contiguous tile chunk per XCD
    const int nwg = NBX * 234;
    const int orig = blockIdx.y * NBX + blockIdx.x;
    const int qq = nwg >> 3, rr = nwg & 7;
    const int xcd = orig & 7, idx = orig >> 3;
    const int swz = (xcd < rr ? xcd * (qq + 1) : rr * (qq + 1) + (xcd - rr) * qq) + idx;
    const int n0 = (swz % NBX) * 256;
    const int m0 = (swz / NBX) * 256;

    const int tid = threadIdx.x, lane = tid & 63, wv = tid >> 6;
    const int wm = (wv >> 2) * 128, wn = (wv & 3) * 64;
    const int lm = lane & 15, kq = lane >> 4;
    const int rblk = lane >> 3;
    const int sc = (((lane & 7) ^ rblk) << 3);          // pre-swizzled source granule

    // staging source bases (per lane)
    const unsigned short* bsrc = B + (size_t)(n0 + wv * 32 + rblk) * 512 + sc;
    const int ar0 = (wv & 4) ? (128 + (wv & 3) * 16) : (wv * 16);
    const unsigned short* asrc = A + (size_t)(m0 + ar0 + rblk) * LDA + sc;

    f32x4 acc[8][4] = {};

    // prologue: stage K-tile 0 into buffer 0, full drain (first tile only)
    gload16(&Bs0[wv * 32 +  0][0], bsrc + (size_t) 0 * 512);
    gload16(&Bs0[wv * 32 +  8][0], bsrc + (size_t) 8 * 512);
    gload16(&Bs0[wv * 32 + 16][0], bsrc + (size_t)16 * 512);
    gload16(&Bs0[wv * 32 + 24][0], bsrc + (size_t)24 * 512);
    gload16(&As0[ar0 +  0][0], asrc);
    gload16(&As0[ar0 +  8][0], asrc + (size_t) 8 * LDA);
    gload16(&As0[ar0 + 64][0], asrc + (size_t)64 * LDA);
    gload16(&As0[ar0 + 72][0], asrc + (size_t)72 * LDA);
    asm volatile("s_waitcnt vmcnt(0)" ::: "memory");
    __builtin_amdgcn_s_barrier();
    __builtin_amdgcn_sched_barrier(0);

    // tiles 0..5: rolled pairs with literal buffer refs
    for (int kt = 0; kt < 6; kt += 2) {
        KTILE(As0, Bs0, As1, Bs1, (kt + 1) * 64, true, false);
        KTILE(As1, Bs1, As0, Bs0, (kt + 2) * 64, true, false);
    }
    // tiles 6,7 peeled
    KTILE(As0, Bs0, As1, Bs1, 7 * 64, true, false);
    KTILE(As1, Bs1, As0, Bs0, 0, false, true);

    // epilogue: swapped operands -> lane holds 4 consecutive COLS of row (wm+mi*16+lm)
    const int cr = kq << 2;
    if constexpr (!PROJ) {
        #pragma unroll
        for (int ni = 0; ni < 4; ++ni) {
            const int col = n0 + wn + ni * 16 + cr;
            const float4 bb = *(const float4*)&bias[col];
            #pragma unroll
            for (int mi = 0; mi < 8; ++mi) {
                const size_t off = (size_t)(m0 + wm + mi * 16 + lm) * N3 + col;
                uint2 pk;
                pk.x = (unsigned)f2bf(acc[mi][ni][0] + bb.x) | ((unsigned)f2bf(acc[mi][ni][1] + bb.y) << 16);
                pk.y = (unsigned)f2bf(acc[mi][ni][2] + bb.z) | ((unsigned)f2bf(acc[mi][ni][3] + bb.w) << 16);
                *(uint2*)&outh[off] = pk;
            }
        }
    } else {
        #pragma unroll
        for (int ni = 0; ni < 4; ++ni) {
            const int col = n0 + wn + ni * 16 + cr;
            const float4 bb = *(const float4*)&bias[col];
            #pragma unroll
            for (int mi = 0; mi < 8; ++mi) {
                const size_t off = (size_t)(m0 + wm + mi * 16 + lm) * 512 + col;
                float4 rs = *(const float4*)&resid[off];
                float4 o;
                o.x = rs.x + acc[mi][ni][0] + bb.x;
                o.y = rs.y + acc[mi][ni][1] + bb.y;
                o.z = rs.z + acc[mi][ni][2] + bb.z;
                o.w = rs.w + acc[mi][ni][3] + bb.w;
                *(float4*)&outf[off] = o;      // resid may alias outf (same element)
            }
        }
    }
}

// ---------------------------------------------------------------- MFMA attention, S in {48, 96}
template<int S, int MODE>
__global__ __launch_bounds__(256) void attn_big(
    unsigned short* __restrict__ qkv,
    const float* __restrict__ lat_grid, const float* __restrict__ lon_grid)
{
    constexpr int NQ  = S / 16;
    constexpr int SKP = (S + 31) & ~31;
    constexpr int VST = SKP + 8;
    __shared__ alignas(16) unsigned short qs[S][40];
    __shared__ alignas(16) unsigned short ks[S][40];
    __shared__ alignas(16) unsigned short vT[32][VST];
    __shared__ alignas(16) unsigned short pb[4][16][VST];

    const int n = blockIdx.x, h = blockIdx.y;
    const int tid = threadIdx.x, lane = tid & 63, wv = tid >> 6;
    int base, step;
    if (MODE == 0) { int l = n / 96, w = n - l * 96; base = l * 4608 + w; step = 96; }
    else           { base = n * 96; step = 1; }

    const float SCALE = 0.17677669529663689f;   // 1/sqrt(32)
    for (int idx = tid; idx < S * 16; idx += 256) {
        int s = idx >> 4, i = idx & 15;
        size_t ro = (size_t)(base + s * step) * N3 + h * 32;
        unsigned qp = *(const unsigned*)(qkv + ro + 2 * i);
        unsigned kp = *(const unsigned*)(qkv + ro + 512 + 2 * i);
        unsigned vp = *(const unsigned*)(qkv + ro + 1024 + 2 * i);
        float coord;
        if (MODE == 0) {
            float la = lat_grid[s];
            coord = fminf(fmaxf(la, -PI_F / 2 + 1e-6f), PI_F / 2 - 1e-6f);
        } else {
            float xp = lon_grid[s] + PI_F;
            coord = xp - floorf(xp * (0.5f / PI_F)) * (2.f * PI_F) - PI_F;
        }
        float ph = coord * exp2f(-(float)i * 0.83048202372f); // log2(1e4)/16
        float sn = sinf(ph), cs = cosf(ph);
        float q1 = bf2f((unsigned short)qp), q2 = bf2f((unsigned short)(qp >> 16));
        float k1 = bf2f((unsigned short)kp), k2 = bf2f((unsigned short)(kp >> 16));
        qs[s][i]      = f2bf((q1 * cs - q2 * sn) * SCALE);
        qs[s][16 + i] = f2bf((q1 * sn + q2 * cs) * SCALE);
        ks[s][i]      = f2bf(k1 * cs - k2 * sn);
        ks[s][16 + i] = f2bf(k1 * sn + k2 * cs);
        vT[2 * i][s]     = (unsigned short)vp;
        vT[2 * i + 1][s] = (unsigned short)(vp >> 16);
    }
    if (SKP > S) {
        for (int idx = tid; idx < 32 * (SKP - S); idx += 256)
            vT[idx / (SKP - S)][S + idx % (SKP - S)] = 0;
    }
    __syncthreads();

    const int lm = lane & 15, ko = (lane >> 4) * 8, q4 = (lane >> 4) * 4;
    f32x4 zero = {0.f, 0.f, 0.f, 0.f};
    bf16x8 vf[SKP / 32][2];
    #pragma unroll
    for (int u2 = 0; u2 < SKP / 32; ++u2)
        #pragma unroll
        for (int nh2 = 0; nh2 < 2; ++nh2)
            vf[u2][nh2] = *(const bf16x8*)&vT[nh2 * 16 + lm][u2 * 32 + ko];
    if (SKP > S) {
        for (int idx = lane; idx < 16 * (SKP - S); idx += 64)
            pb[wv][idx / (SKP - S)][S + idx % (SKP - S)] = 0;
    }

    for (int t = wv; t < NQ; t += 4) {
        bf16x8 aq = *(const bf16x8*)&qs[t * 16 + lm][ko];
        f32x4 c[NQ];
        #pragma unroll
        for (int u = 0; u < NQ; ++u) {
            bf16x8 bk = *(const bf16x8*)&ks[u * 16 + lm][ko];
            c[u] = __builtin_amdgcn_mfma_f32_16x16x32_bf16(aq, bk, zero, 0, 0, 0);
        }
        float mr[4] = {-1e30f, -1e30f, -1e30f, -1e30f}, sm[4] = {0.f, 0.f, 0.f, 0.f};
        #pragma unroll
        for (int u = 0; u < NQ; ++u)
            #pragma unroll
            for (int r = 0; r < 4; ++r) mr[r] = fmaxf(mr[r], c[u][r]);
        #pragma unroll
        for (int r = 0; r < 4; ++r)
            #pragma unroll
            for (int off = 1; off < 16; off <<= 1)
                mr[r] = fmaxf(mr[r], __shfl_xor(mr[r], off, 64));
        #pragma unroll
        for (int u = 0; u < NQ; ++u)
            #pragma unroll
            for (int r = 0; r < 4; ++r) {
                float e = __expf(c[u][r] - mr[r]);
                c[u][r] = e; sm[r] += e;
            }
        #pragma unroll
        for (int r = 0; r < 4; ++r) {
            #pragma unroll
            for (int off = 1; off < 16; off <<= 1)
                sm[r] += __shfl_xor(sm[r], off, 64);
            sm[r] = 1.f / sm[r];
        }
        #pragma unroll
        for (int u = 0; u < NQ; ++u)
            #pragma unroll
            for (int r = 0; r < 4; ++r)
                pb[wv][q4 + r][u * 16 + lm] = f2bf(c[u][r] * sm[r]);
        __builtin_amdgcn_wave_barrier();
        f32x4 o0 = zero, o1 = zero;
        #pragma unroll
        for (int u2 = 0; u2 < SKP / 32; ++u2) {
            bf16x8 ap = *(const bf16x8*)&pb[wv][lm][u2 * 32 + ko];
            o0 = __builtin_amdgcn_mfma_f32_16x16x32_bf16(ap, vf[u2][0], o0, 0, 0, 0);
            o1 = __builtin_amdgcn_mfma_f32_16x16x32_bf16(ap, vf[u2][1], o1, 0, 0, 0);
        }
        __builtin_amdgcn_wave_barrier();
        #pragma unroll
        for (int r = 0; r < 4; ++r) {
            int row = t * 16 + q4 + r;
            size_t ro = (size_t)(base + row * step) * N3 + h * 32;
            qkv[ro + lm]      = f2bf(o0[r]);
            qkv[ro + 16 + lm] = f2bf(o1[r]);
        }
    }
}

// ---------------------------------------------------------------- MFMA attention, S=13 (lev)
__global__ __launch_bounds__(256) void attn_small(unsigned short* __restrict__ qkv)
{
    __shared__ alignas(16) unsigned short qs[4][16][40];
    __shared__ alignas(16) unsigned short ks[4][16][40];
    __shared__ alignas(16) unsigned short vT[4][32][40];
    __shared__ alignas(16) unsigned short pb[4][16][40];
    const int tid = threadIdx.x, lane = tid & 63, wv = tid >> 6;
    const int pair = blockIdx.x * 4 + wv;
    const int n = pair >> 4, h = pair & 15;
    const int base = n, step = 4608;

    for (int idx = lane; idx < 13 * 16; idx += 64) {
        int s = idx >> 4, i = idx & 15;
        size_t ro = (size_t)(base + s * step) * N3 + h * 32;
        *(unsigned*)&qs[wv][s][2 * i] = *(const unsigned*)(qkv + ro + 2 * i);
        *(unsigned*)&ks[wv][s][2 * i] = *(const unsigned*)(qkv + ro + 512 + 2 * i);
        unsigned vp = *(const unsigned*)(qkv + ro + 1024 + 2 * i);
        vT[wv][2 * i][s]     = (unsigned short)vp;
        vT[wv][2 * i + 1][s] = (unsigned short)(vp >> 16);
    }
    for (int idx = lane; idx < 32 * 19; idx += 64) {
        int d = idx / 19, k = 13 + idx % 19;
        vT[wv][d][k] = 0;
    }
    for (int idx = lane; idx < 16 * 16; idx += 64)
        pb[wv][idx >> 4][16 + (idx & 15)] = 0;
    __syncthreads();

    const int lm = lane & 15, ko = (lane >> 4) * 8, q4 = (lane >> 4) * 4;
    f32x4 zero = {0.f, 0.f, 0.f, 0.f};
    bf16x8 aq = *(const bf16x8*)&qs[wv][lm][ko];
    bf16x8 bk = *(const bf16x8*)&ks[wv][lm][ko];
    f32x4 c = __builtin_amdgcn_mfma_f32_16x16x32_bf16(aq, bk, zero, 0, 0, 0);
    const float SCALE = 0.17677669529663689f;
    float cf[4], mr[4], sm[4];
    bool colok = (lm < 13);
    #pragma unroll
    for (int r = 0; r < 4; ++r) {
        cf[r] = colok ? c[r] * SCALE : -1e30f;
        mr[r] = cf[r];
    }
    #pragma unroll
    for (int r = 0; r < 4; ++r)
        #pragma unroll
        for (int off = 1; off < 16; off <<= 1)
            mr[r] = fmaxf(mr[r], __shfl_xor(mr[r], off, 64));
    #pragma unroll
    for (int r = 0; r < 4; ++r) { cf[r] = __expf(cf[r] - mr[r]); sm[r] = cf[r]; }
    #pragma unroll
    for (int r = 0; r < 4; ++r) {
        #pragma unroll
        for (int off = 1; off < 16; off <<= 1)
            sm[r] += __shfl_xor(sm[r], off, 64);
        sm[r] = 1.f / sm[r];
    }
    #pragma unroll
    for (int r = 0; r < 4; ++r)
        pb[wv][q4 + r][lm] = f2bf(cf[r] * sm[r]);
    __builtin_amdgcn_wave_barrier();
    bf16x8 ap  = *(const bf16x8*)&pb[wv][lm][ko];
    bf16x8 vf0 = *(const bf16x8*)&vT[wv][lm][ko];
    bf16x8 vf1 = *(const bf16x8*)&vT[wv][16 + lm][ko];
    f32x4 o0 = __builtin_amdgcn_mfma_f32_16x16x32_bf16(ap, vf0, zero, 0, 0, 0);
    f32x4 o1 = __builtin_amdgcn_mfma_f32_16x16x32_bf16(ap, vf1, zero, 0, 0, 0);
    #pragma unroll
    for (int r = 0; r < 4; ++r) {
        int row = q4 + r;
        if (row < 13) {
            size_t ro = (size_t)(base + row * step) * N3 + h * 32;
            qkv[ro + lm]      = f2bf(o0[r]);
            qkv[ro + 16 + lm] = f2bf(o1[r]);
        }
    }
}

// ---------------------------------------------------------------- launch
extern "C" void kernel_launch(void* const* d_in, const int* in_sizes, int n_in,
                              void* d_out, int out_size, void* d_ws, size_t ws_size,
                              hipStream_t stream) {
    const float* x        = (const float*)d_in[0];
    const float* lat_grid = (const float*)d_in[1];
    const float* lon_grid = (const float*)d_in[2];
    const float* qkv_w[3] = {(const float*)d_in[3], (const float*)d_in[5], (const float*)d_in[7]};
    const float* qkv_b[3] = {(const float*)d_in[4], (const float*)d_in[6], (const float*)d_in[8]};
    const float* proj_w   = (const float*)d_in[9];
    const float* proj_b   = (const float*)d_in[10];
    const float* g[3]     = {(const float*)d_in[11], (const float*)d_in[13], (const float*)d_in[15]};
    const float* bln[3]   = {(const float*)d_in[12], (const float*)d_in[14], (const float*)d_in[16]};
    float* tok = (float*)d_out;

    unsigned short* wT0 = (unsigned short*)d_ws;
    unsigned short* wT1 = wT0 + 1536 * 512;
    unsigned short* wT2 = wT1 + 1536 * 512;
    unsigned short* pT  = wT2 + 1536 * 512;
    unsigned short* lnb = pT + 512 * 512;
    unsigned short* qkv = lnb + (size_t)MTOK * 512;
    unsigned short* wT[3] = {wT0, wT1, wT2};

    transpose_w<<<dim3(8, 24), 256, 0, stream>>>(qkv_w[0], wT0, 1536);
    transpose_w<<<dim3(8, 24), 256, 0, stream>>>(qkv_w[1], wT1, 1536);
    transpose_w<<<dim3(8, 24), 256, 0, stream>>>(qkv_w[2], wT2, 1536);
    transpose_w<<<dim3(8, 8),  256, 0, stream>>>(proj_w, pT, 512);

    for (int b = 0; b < 3; ++b) {
        const float* src = (b == 0) ? x : tok;
        ln_apply<<<MTOK / 4, 256, 0, stream>>>(src, g[b], bln[b], lnb);
        gemm8p<512, 6, false><<<dim3(6, MTOK / 256), 512, 0, stream>>>(
            lnb, wT[b], qkv_b[b], nullptr, nullptr, qkv);
        if (b == 0)
            attn_big<48, 0><<<dim3(L_DIM * W_DIM, NH), 256, 0, stream>>>(qkv, lat_grid, lon_grid);
        else if (b == 1)
            attn_big<96, 1><<<dim3(L_DIM * H_DIM, NH), 256, 0, stream>>>(qkv, lat_grid, lon_grid);
        else
            attn_small<<<(H_DIM * W_DIM * NH) / 4, 256, 0, stream>>>(qkv);
        gemm8p<1536, 2, true><<<dim3(2, MTOK / 256), 512, 0, stream>>>(
            qkv, pT, proj_b, src, tok, nullptr);
    }
}